// Round 11
// baseline (5335.411 us; speedup 1.0000x reference)
//
#include <hip/hip_runtime.h>
#include <hip/hip_bf16.h>
#include <hip/hip_cooperative_groups.h>

namespace cg = cooperative_groups;

// LSTM_66443144069713: 3-layer biLSTM, B=256 T=512 H=192 E=128, V=20000.
// Round-11: one cooperative persistent kernel per layer. WGs 0-31 run the full
// 512-step recurrence (r10's proven inner loop; W_hh in VGPRs loaded once,
// h/c persist in LDS/regs); WGs 32-255 produce gx chunk c while consumers eat
// chunk c-1 (ping-pong). Chunk handoff = grid.sync() (release wbl2) + consumer
// agent acquire fence (inv) -- launch-boundary coherence at barrier cost.

typedef _Float16 f16;
typedef unsigned int u32;
typedef _Float16 f16x8 __attribute__((ext_vector_type(8)));
typedef float f32x4 __attribute__((ext_vector_type(4)));

__device__ __forceinline__ float sigm(float x) {
  float e = __builtin_amdgcn_exp2f(x * -1.44269504088896f);
  return __builtin_amdgcn_rcpf(1.0f + e);
}
__device__ __forceinline__ float tanh_(float x) {
  float e = __builtin_amdgcn_exp2f(x * -2.88539008177793f);
  return __builtin_fmaf(2.0f, __builtin_amdgcn_rcpf(1.0f + e), -1.0f);
}

// ---------- small utility kernels ----------

__global__ void castk(const float* __restrict__ s, f16* __restrict__ d, int n) {
  int i = blockIdx.x * 256 + threadIdx.x;
  int st = gridDim.x * 256;
  for (; i < n; i += st) d[i] = (f16)s[i];
}

// W_hh (f32 [2][768][192]) -> f16 fragment layout [dir][w12][g][kk][lane][8]
__global__ void castwhh(const float* __restrict__ src, f16* __restrict__ dst) {
  int o = blockIdx.x * 256 + threadIdx.x;  // < 294912
  int e = o & 7, rest = o >> 3;
  int l = rest & 63; rest >>= 6;
  int kk = rest % 6; rest /= 6;
  int g = rest & 3; rest >>= 2;
  int w = rest % 12; int dir = rest / 12;
  int lo16 = l & 15, lhi = l >> 4;
  dst[o] = (f16)src[(size_t)(dir * 768 + g * 192 + w * 16 + lo16) * 192 + kk * 32 + lhi * 8 + e];
}

// A0[t*256+b][k] = fp16(emb[x[b][t]][k])
__global__ void embedk(const int* __restrict__ x, const float* __restrict__ emb,
                       f16* __restrict__ A0) {
  int row = blockIdx.x * 8 + (threadIdx.x >> 5);
  int t = row >> 8, b = row & 255;
  int xi = x[b * 512 + t];
  int c = (threadIdx.x & 31) * 4;
  float4 v = *(const float4*)(emb + (size_t)xi * 128 + c);
  union { f16 h[4]; uint2 u; } p;
  p.h[0] = (f16)v.x; p.h[1] = (f16)v.y; p.h[2] = (f16)v.z; p.h[3] = (f16)v.w;
  *(uint2*)(A0 + (size_t)row * 128 + c) = p.u;
}

// ---------- persistent per-layer cooperative kernel ----------
// gx dword index: ((((dir*TC+tl)*16 + b16)*12 + w12)*512) + (g*2+qq)*64 + lane,
//   lane = ((b&15)>>2)*16 + (u&15); dword packs batch rows 2qq (lo), 2qq+1 (hi).
template <int KD>
__global__ __launch_bounds__(768, 3)
void persistk(const f16* __restrict__ in, const f16* __restrict__ Bt,
              const float* __restrict__ bias,
              u32* __restrict__ gx0, u32* __restrict__ gx1,
              const f16* __restrict__ whh16,
              f16* __restrict__ outh, float* __restrict__ hT,
              int NC, int TC, int wOut, int wHT) {
  union SMem {
    struct { uint4 A[512]; uint4 B[1536]; } g;   // 8KB + 24KB gemm staging
    f16 hb[2][16 * 200];                         // 12.8KB recurrence h
  };
  __shared__ __align__(16) SMem sm;
  cg::grid_group grid = cg::this_grid();
  const int wg = blockIdx.x;
  const int tid = threadIdx.x;
  const int l = tid & 63, w = tid >> 6;
  const int lo16 = l & 15, lhi = l >> 4;
  const int TCm1 = TC - 1;

  if (wg < 32) {
    // ================= recurrence consumer (whole layer) =================
    const int dir = wg & 1, bblk = wg >> 1;
    const int u0 = w * 16;
    const int bb = bblk * 16 + lhi * 4;
    const int dc = dir * 192;
    const int hb0 = lhi * 800 + u0 + lo16;  // (lhi*4)*200 + ...

    f16x8 wf[4][6];
#pragma unroll
    for (int g = 0; g < 4; ++g)
#pragma unroll
      for (int kk = 0; kk < 6; ++kk)
        wf[g][kk] = *(const f16x8*)(whh16 + ((((size_t)dir * 12 + w) * 4 + g) * 6 + kk) * 512 + l * 8);

    {
      f16* hz = (f16*)sm.hb;
      for (int i = tid; i < 2 * 16 * 200; i += 768) hz[i] = (f16)0.f;
    }
    __syncthreads();
    float cq[4] = {0.f, 0.f, 0.f, 0.f};

    f16* outp = outh + ((size_t)(dir ? 511 : 0) * 256 + bb) * 384 + dc + u0 + lo16;
    const ptrdiff_t ostep = dir ? -(ptrdiff_t)98304 : (ptrdiff_t)98304;

    grid.sync();  // chunk 0 published
    __builtin_amdgcn_fence(__ATOMIC_ACQUIRE, "agent");

    u32 ga[8], gb[8];
    for (int c = 0; c < NC; ++c) {
      const u32* __restrict__ gxR = (c & 1) ? gx1 : gx0;
      const int lastc = (wHT && c == NC - 1) ? 1 : 0;
      {  // prefetch step 0 of this chunk
        const int tl0 = dir ? TCm1 : 0;
        size_t wb = ((((size_t)dir * TC + tl0) * 16 + bblk) * 12 + w) * 512;
#pragma unroll
        for (int k2 = 0; k2 < 8; ++k2) ga[k2] = gxR[wb + k2 * 64 + l];
      }

#define RSTEP(S, CUR, NXT)                                                         \
  do {                                                                             \
    {                                                                              \
      int snx = ((S) + 1 < TC) ? (S) + 1 : (S);                                    \
      int tln = dir ? (TCm1 - snx) : snx;                                          \
      size_t wb = ((((size_t)dir * TC + tln) * 16 + bblk) * 12 + w) * 512;         \
      _Pragma("unroll") for (int k2 = 0; k2 < 8; ++k2) NXT[k2] = gxR[wb + k2 * 64 + l]; \
    }                                                                              \
    f32x4 ac[4];                                                                   \
    _Pragma("unroll") for (int g_ = 0; g_ < 4; ++g_) {                             \
      union { u32 u; f16 h[2]; } p0, p1;                                           \
      p0.u = CUR[2 * g_]; p1.u = CUR[2 * g_ + 1];                                  \
      ac[g_][0] = (float)p0.h[0]; ac[g_][1] = (float)p0.h[1];                      \
      ac[g_][2] = (float)p1.h[0]; ac[g_][3] = (float)p1.h[1];                      \
    }                                                                              \
    {                                                                              \
      const f16* hcur = sm.hb[(S) & 1];                                            \
      _Pragma("unroll") for (int kk = 0; kk < 6; ++kk) {                           \
        f16x8 av = *(const f16x8*)(hcur + lo16 * 200 + kk * 32 + lhi * 8);         \
        ac[0] = __builtin_amdgcn_mfma_f32_16x16x32_f16(av, wf[0][kk], ac[0], 0, 0, 0); \
        ac[1] = __builtin_amdgcn_mfma_f32_16x16x32_f16(av, wf[1][kk], ac[1], 0, 0, 0); \
        ac[2] = __builtin_amdgcn_mfma_f32_16x16x32_f16(av, wf[2][kk], ac[2], 0, 0, 0); \
        ac[3] = __builtin_amdgcn_mfma_f32_16x16x32_f16(av, wf[3][kk], ac[3], 0, 0, 0); \
      }                                                                            \
    }                                                                              \
    f16* hnew = sm.hb[((S) + 1) & 1];                                              \
    _Pragma("unroll") for (int q = 0; q < 4; ++q) {                                \
      float iv = sigm(ac[0][q]), fv = sigm(ac[1][q]);                              \
      float gv = tanh_(ac[2][q]), ov = sigm(ac[3][q]);                             \
      cq[q] = fv * cq[q] + iv * gv;                                                \
      float hv = ov * tanh_(cq[q]);                                                \
      f16 hh = (f16)hv;                                                            \
      hnew[hb0 + q * 200] = hh;                                                    \
      if (wOut) outp[q * 384] = hh;                                                \
      if (lastc && (S) == TCm1)                                                    \
        hT[((size_t)dir * 256 + bb + q) * 192 + u0 + lo16] = hv;                   \
    }                                                                              \
    outp += ostep;                                                                 \
    asm volatile("s_waitcnt lgkmcnt(0)" ::: "memory");                             \
    __builtin_amdgcn_s_barrier();                                                  \
    asm volatile("" ::: "memory");                                                 \
  } while (0)

      for (int s = 0; s < TC; s += 2) {
        RSTEP(s, ga, gb);
        RSTEP(s + 1, gb, ga);
      }
#undef RSTEP
      grid.sync();  // chunk c consumed; chunk c+1 published
      __builtin_amdgcn_fence(__ATOMIC_ACQUIRE, "agent");
    }
    return;
  }

  // ================= GEMM producer (one chunk per iteration) =================
  const int gid = wg - 32;            // 0..223
  const int RT = TC * 4;              // 64-row tiles per direction
  const int ntiles = RT * 8;          // 2 dirs * RT * 4 gates
  const int wmm = w / 6, wn = w % 6;  // 2x6 waves: 32 rows x 32 cols each
  constexpr int NKc = KD / 64;

  for (int c = 0; c < NC; ++c) {
    u32* __restrict__ gxW = (c & 1) ? gx1 : gx0;
    const int tbf = c * TC, tbb = 512 - (c + 1) * TC;

    for (int tt = gid; tt < ntiles; tt += 224) {
      const int g = tt & 3;
      const int r = (tt >> 2) % RT;
      const int dir = (tt >> 2) / RT;
      const size_t ar0 = (size_t)(dir ? tbb : tbf) * 256 + r * 64;  // A row base
      const int btr0 = dir * 768 + g * 192;                         // Bt row base

      float bj[2];
#pragma unroll
      for (int j = 0; j < 2; ++j) bj[j] = bias[btr0 + wn * 32 + j * 16 + lo16];

      f32x4 acc[2][2] = {};
      uint4 a0v, b0v, b1v;

#define LDG(ko_)                                                                   \
  do {                                                                             \
    if (tid < 512) {                                                               \
      int row = tid >> 3, sl = tid & 7, ch = sl ^ (row & 7);                       \
      a0v = *(const uint4*)(in + (ar0 + row) * KD + (ko_)*64 + ch * 8);            \
    }                                                                              \
    { int row = tid >> 3, sl = tid & 7, ch = sl ^ (row & 7);                       \
      b0v = *(const uint4*)(Bt + (size_t)(btr0 + row) * KD + (ko_)*64 + ch * 8); } \
    { int idx = tid + 768; int row = idx >> 3, sl = idx & 7, ch = sl ^ (row & 7);  \
      b1v = *(const uint4*)(Bt + (size_t)(btr0 + row) * KD + (ko_)*64 + ch * 8); } \
  } while (0)

      LDG(0);
      for (int ko = 0; ko < NKc; ++ko) {
        __syncthreads();
        if (tid < 512) sm.g.A[tid] = a0v;
        sm.g.B[tid] = b0v;
        sm.g.B[tid + 768] = b1v;
        __syncthreads();
        if (ko + 1 < NKc) LDG(ko + 1);
#pragma unroll
        for (int kk = 0; kk < 2; ++kk) {
          f16x8 af[2], bf[2];
#pragma unroll
          for (int i = 0; i < 2; ++i) {
            int rowA = wmm * 32 + i * 16 + lo16;
            int slA = (kk * 4 + lhi) ^ (rowA & 7);
            af[i] = *(const f16x8*)((const char*)sm.g.A + rowA * 128 + slA * 16);
          }
#pragma unroll
          for (int j = 0; j < 2; ++j) {
            int colB = wn * 32 + j * 16 + lo16;
            int slB = (kk * 4 + lhi) ^ (colB & 7);
            bf[j] = *(const f16x8*)((const char*)sm.g.B + colB * 128 + slB * 16);
          }
#pragma unroll
          for (int i = 0; i < 2; ++i)
#pragma unroll
            for (int j = 0; j < 2; ++j)
              acc[i][j] = __builtin_amdgcn_mfma_f32_16x16x32_f16(af[i], bf[j], acc[i][j], 0, 0, 0);
        }
      }
#undef LDG

      // epilogue -> gxW (coalesced u32 stores)
#pragma unroll
      for (int i = 0; i < 2; ++i) {
        int rl = r * 64 + wmm * 32 + i * 16 + lhi * 4;
        int tl = rl >> 8;
        int b16 = (rl & 255) >> 4;
#pragma unroll
        for (int j = 0; j < 2; ++j) {
          int w12 = wn * 2 + j;
          size_t base = ((((size_t)dir * TC + tl) * 16 + b16) * 12 + w12) * 512;
#pragma unroll
          for (int qq = 0; qq < 2; ++qq) {
            union { f16 h[2]; u32 u; } p;
            p.h[0] = (f16)(acc[i][j][2 * qq] + bj[j]);
            p.h[1] = (f16)(acc[i][j][2 * qq + 1] + bj[j]);
            gxW[base + (g * 2 + qq) * 64 + l] = p.u;
          }
        }
      }
      __syncthreads();  // protect LDS reuse across tile loop
    }
    grid.sync();  // publish chunk c (release: wbl2 via threadfence inside)
  }
  grid.sync();  // matches consumer's final sync (while it eats chunk NC-1)
}

__global__ void fck(const float* __restrict__ hT, const float* __restrict__ w,
                    const float* __restrict__ fb, float* __restrict__ out) {
  int b = blockIdx.x * 64 + threadIdx.x;
  float a = fb[0];
#pragma unroll 4
  for (int u = 0; u < 192; ++u)
    a += w[u] * hT[(size_t)b * 192 + u] + w[192 + u] * hT[49152 + (size_t)b * 192 + u];
  out[b] = a;
}

extern "C" void kernel_launch(void* const* d_in, const int* in_sizes, int n_in,
                              void* d_out, int out_size, void* d_ws, size_t ws_size,
                              hipStream_t stream) {
  (void)in_sizes; (void)n_in; (void)out_size;
  const int* x = (const int*)d_in[0];
  const float* emb = (const float*)d_in[1];
  const float* Wih0 = (const float*)d_in[2];
  const float* Whh0 = (const float*)d_in[3];
  const float* b0 = (const float*)d_in[4];
  const float* Wihr = (const float*)d_in[5];
  const float* Whhr = (const float*)d_in[6];
  const float* br = (const float*)d_in[7];
  const float* fcw = (const float*)d_in[8];
  const float* fcb = (const float*)d_in[9];
  float* out = (float*)d_out;

  const size_t hB = 100663296ull;  // [512][256][384] f16
  const size_t fixedB = 2 * hB + 1179648ull + 589824ull + 393216ull;

  int TC = (ws_size >= fixedB + 2ull * 16 * 786432ull) ? 16 : 8;  // proven TC=16 fits
  const int NC = 512 / TC;
  const size_t chunkB = (size_t)TC * 786432ull;

  char* ws = (char*)d_ws;
  u32* gx0 = (u32*)ws;
  u32* gx1 = (u32*)(ws + chunkB);
  size_t off = 2 * chunkB;
  f16* h0 = (f16*)(ws + off); off += hB;
  f16* h1 = (f16*)(ws + off); off += hB;
  f16* A0 = h1;  // alias: A0 dead before h1's first write (layer-1 lstm)
  f16* Bt = (f16*)(ws + off); off += 1179648ull;     // [1536][KD] f16 (per-layer)
  f16* whh16 = (f16*)(ws + off); off += 589824ull;   // fragment layout (per-layer)
  float* hTp = (float*)(ws + off); off += 393216ull; // [2][256][192] f32

  embedk<<<16384, 256, 0, stream>>>(x, emb, A0);

  for (int layer = 0; layer < 3; ++layer) {
    if (layer == 0) {
      castk<<<192, 256, 0, stream>>>(Wih0, Bt, 196608);
      castwhh<<<1152, 256, 0, stream>>>(Whh0, whh16);
    } else {
      castk<<<1152, 256, 0, stream>>>(Wihr + (size_t)(layer - 1) * 589824, Bt, 589824);
      castwhh<<<1152, 256, 0, stream>>>(Whhr + (size_t)(layer - 1) * 294912, whh16);
    }

    const f16* a_in = (layer == 0) ? A0 : (layer == 1 ? h0 : h1);
    const f16* a_bt = Bt;
    const float* a_bias = (layer == 0) ? b0 : (br + (layer - 1) * 1536);
    u32* a_g0 = gx0;
    u32* a_g1 = gx1;
    const f16* a_whh = whh16;
    f16* a_out = (layer == 1) ? h1 : h0;  // layer 2: unused (wOut=0)
    float* a_ht = hTp;
    int a_nc = NC, a_tc = TC;
    int a_wout = (layer < 2) ? 1 : 0;
    int a_wht = (layer == 2) ? 1 : 0;
    void* ka[12] = {&a_in, &a_bt, &a_bias, &a_g0, &a_g1, &a_whh,
                    &a_out, &a_ht, &a_nc, &a_tc, &a_wout, &a_wht};
    if (layer == 0)
      hipLaunchCooperativeKernel(persistk<128>, dim3(256), dim3(768), ka, 0u, stream);
    else
      hipLaunchCooperativeKernel(persistk<384>, dim3(256), dim3(768), ka, 0u, stream);
  }

  fck<<<4, 64, 0, stream>>>(hTp, fcw, fcb, out);
}

// Round 12
// 2917.627 us; speedup vs baseline: 1.8287x; 1.8287x over previous
//
#include <hip/hip_runtime.h>
#include <hip/hip_bf16.h>

// LSTM_66443144069713: 3-layer biLSTM, B=256 T=512 H=192 E=128, V=20000.
// Round-12: r10's launch-boundary chunk pipeline (proven fastest; r11 proved
// grid.sync costs 2x a launch boundary). Upgrades: fused gate math (8 trans/
// cell, r8-proven), gx segment layout l*8+g2qq -> 2x dwordx4 consumer loads /
// 4x dwordx2 producer stores, incremental gx pointer, merged cast launch.

typedef _Float16 f16;
typedef unsigned int u32;
typedef _Float16 f16x8 __attribute__((ext_vector_type(8)));
typedef float f32x4 __attribute__((ext_vector_type(4)));

typedef union { uint4 v[2]; u32 d[8]; } gx8;

// ---------- small utility kernels ----------

// per-layer weight prep: W_ih cast (nbt elems) + W_hh fragment cast (294912)
__global__ void castboth(const float* __restrict__ wih, f16* __restrict__ bt, int nbt,
                         const float* __restrict__ whh, f16* __restrict__ w16) {
  int i = blockIdx.x * 256 + threadIdx.x;
  if (i < nbt) bt[i] = (f16)wih[i];
  int o = i - nbt;
  if (o >= 0 && o < 294912) {
    int e = o & 7, rest = o >> 3;
    int l = rest & 63; rest >>= 6;
    int kk = rest % 6; rest /= 6;
    int g = rest & 3; rest >>= 2;
    int w = rest % 12; int dir = rest / 12;
    int lo16 = l & 15, lhi = l >> 4;
    w16[o] = (f16)whh[(size_t)(dir * 768 + g * 192 + w * 16 + lo16) * 192 + kk * 32 + lhi * 8 + e];
  }
}

// A0[t*256+b][k] = fp16(emb[x[b][t]][k])
__global__ void embedk(const int* __restrict__ x, const float* __restrict__ emb,
                       f16* __restrict__ A0) {
  int row = blockIdx.x * 8 + (threadIdx.x >> 5);
  int t = row >> 8, b = row & 255;
  int xi = x[b * 512 + t];
  int c = (threadIdx.x & 31) * 4;
  float4 v = *(const float4*)(emb + (size_t)xi * 128 + c);
  union { f16 h[4]; uint2 u; } p;
  p.h[0] = (f16)v.x; p.h[1] = (f16)v.y; p.h[2] = (f16)v.z; p.h[3] = (f16)v.w;
  *(uint2*)(A0 + (size_t)row * 128 + c) = p.u;
}

// ---------- fused kernel ----------
// gx dword index: seg*512 + l*8 + (g*2+qq), seg = ((dir*TC+tl)*16+b16)*12+w12;
//   lane l = ((b&15)>>2)*16 + (u&15); dword packs batch rows 2qq (lo), 2qq+1 (hi).
template <int KD>
__global__ __launch_bounds__(768)
void fusedk(const f16* __restrict__ in, const f16* __restrict__ Bt,
            const float* __restrict__ bias,
            const u32* __restrict__ gxR, u32* __restrict__ gxW,
            const f16* __restrict__ whh16,
            f16* __restrict__ outh, float* __restrict__ hT,
            f16* __restrict__ carh, float* __restrict__ carc,
            int c, int cg, int NC, int TC, int doLstm, int wOut, int wHT) {
  union SMem {
    struct { uint4 A[512]; uint4 B[1536]; } g;   // 8KB + 24KB gemm staging
    f16 hb[2][16 * 200];                         // 12.8KB recurrence h
  };
  __shared__ __align__(16) SMem sm;
  const int wg = blockIdx.x;
  const int tid = threadIdx.x;
  const int l = tid & 63, w = tid >> 6;
  const int lo16 = l & 15, lhi = l >> 4;
  const int TCm1 = TC - 1;

  if (doLstm && wg < 32) {
    // ================= recurrence part (chunk c) =================
    const int dir = wg & 1, bblk = wg >> 1;
    const int u0 = w * 16;
    const int bb = bblk * 16 + lhi * 4;
    const int dc = dir * 192;
    const int hb0 = lhi * 800 + u0 + lo16;  // (lhi*4)*200 + ...

    f16x8 wf[4][6];
#pragma unroll
    for (int g = 0; g < 4; ++g)
#pragma unroll
      for (int kk = 0; kk < 6; ++kk)
        wf[g][kk] = *(const f16x8*)(whh16 + ((((size_t)dir * 12 + w) * 4 + g) * 6 + kk) * 512 + l * 8);

    float cq[4];
    if (c == 0) {
      f16* hz = (f16*)sm.hb;
      for (int i = tid; i < 2 * 16 * 200; i += 768) hz[i] = (f16)0.f;
#pragma unroll
      for (int q = 0; q < 4; ++q) cq[q] = 0.f;
    } else {
#pragma unroll
      for (int q = 0; q < 4; ++q) {
        size_t ci = ((size_t)dir * 256 + bb + q) * 192 + u0 + lo16;
        cq[q] = carc[ci];
        sm.hb[0][(lhi * 4 + q) * 200 + u0 + lo16] = carh[ci];
      }
    }
    __syncthreads();

    const int tb0 = dir ? (511 - c * TC) : (c * TC);
    f16* outp = outh + ((size_t)tb0 * 256 + bb) * 384 + dc + u0 + lo16;
    const ptrdiff_t ostep = dir ? -(ptrdiff_t)98304 : (ptrdiff_t)98304;
    // gx pointer for this thread at step 0 of the chunk; steps advance by gstep
    const int tl0 = dir ? TCm1 : 0;
    const u32* gxp = gxR + ((((size_t)dir * TC + tl0) * 16 + bblk) * 12 + w) * 512 + l * 8;
    const ptrdiff_t gstep = dir ? -(ptrdiff_t)98304 : (ptrdiff_t)98304;

    gx8 ga, gb;
    ga.v[0] = *(const uint4*)gxp;        // prefetch step 0
    ga.v[1] = *(const uint4*)(gxp + 4);

#define RSTEP(S, CUR, NXT)                                                         \
  do {                                                                             \
    const u32* gnx = ((S) + 1 < TC) ? (gxp + gstep) : gxp;                         \
    NXT.v[0] = *(const uint4*)gnx;                                                 \
    NXT.v[1] = *(const uint4*)(gnx + 4);                                           \
    gxp = gnx;                                                                     \
    f32x4 ac[4];                                                                   \
    _Pragma("unroll") for (int g_ = 0; g_ < 4; ++g_) {                             \
      union { u32 u; f16 h[2]; } p0, p1;                                           \
      p0.u = CUR.d[2 * g_]; p1.u = CUR.d[2 * g_ + 1];                              \
      ac[g_][0] = (float)p0.h[0]; ac[g_][1] = (float)p0.h[1];                      \
      ac[g_][2] = (float)p1.h[0]; ac[g_][3] = (float)p1.h[1];                      \
    }                                                                              \
    {                                                                              \
      const f16* hcur = sm.hb[(S) & 1];                                            \
      _Pragma("unroll") for (int kk = 0; kk < 6; ++kk) {                           \
        f16x8 av = *(const f16x8*)(hcur + lo16 * 200 + kk * 32 + lhi * 8);         \
        ac[0] = __builtin_amdgcn_mfma_f32_16x16x32_f16(av, wf[0][kk], ac[0], 0, 0, 0); \
        ac[1] = __builtin_amdgcn_mfma_f32_16x16x32_f16(av, wf[1][kk], ac[1], 0, 0, 0); \
        ac[2] = __builtin_amdgcn_mfma_f32_16x16x32_f16(av, wf[2][kk], ac[2], 0, 0, 0); \
        ac[3] = __builtin_amdgcn_mfma_f32_16x16x32_f16(av, wf[3][kk], ac[3], 0, 0, 0); \
      }                                                                            \
    }                                                                              \
    f16* hnew = sm.hb[((S) + 1) & 1];                                              \
    _Pragma("unroll") for (int q = 0; q < 4; ++q) {                                \
      float ei = __builtin_amdgcn_exp2f(fminf(ac[0][q] * -1.44269504f, 80.f));     \
      float ef = __builtin_amdgcn_exp2f(fminf(ac[1][q] * -1.44269504f, 80.f));     \
      float eg = __builtin_amdgcn_exp2f(fminf(ac[2][q] * -2.88539008f, 80.f));     \
      float eo = __builtin_amdgcn_exp2f(fminf(ac[3][q] * -1.44269504f, 80.f));     \
      float ig = (1.f - eg) * __builtin_amdgcn_rcpf((1.f + eg) * (1.f + ei));      \
      float fv = __builtin_amdgcn_rcpf(1.f + ef);                                  \
      cq[q] = fv * cq[q] + ig;                                                     \
      float ec = __builtin_amdgcn_exp2f(fminf(cq[q] * -2.88539008f, 80.f));        \
      float hv = (1.f - ec) * __builtin_amdgcn_rcpf((1.f + ec) * (1.f + eo));      \
      f16 hh = (f16)hv;                                                            \
      hnew[hb0 + q * 200] = hh;                                                    \
      if (wOut) outp[q * 384] = hh;                                                \
      if ((S) == TCm1) {                                                           \
        size_t ci = ((size_t)dir * 256 + bb + q) * 192 + u0 + lo16;                \
        carh[ci] = hh;                                                             \
        carc[ci] = cq[q];                                                          \
        if (wHT && c == NC - 1) hT[ci] = hv;                                       \
      }                                                                            \
    }                                                                              \
    outp += ostep;                                                                 \
    asm volatile("s_waitcnt lgkmcnt(0)" ::: "memory");                             \
    __builtin_amdgcn_s_barrier();                                                  \
    asm volatile("" ::: "memory");                                                 \
  } while (0)

    for (int s = 0; s < TC; s += 2) {
      RSTEP(s, ga, gb);
      RSTEP(s + 1, gb, ga);
    }
#undef RSTEP
    return;
  }

  // ================= GEMM part (chunk cg -> gxW), 64-row tiles =================
  if (cg >= NC) return;
  const int pool = doLstm ? 224 : 256;
  const int gid = doLstm ? wg - 32 : wg;
  const int RT = TC * 4;          // 64-row tiles per direction
  const int ntiles = RT * 8;      // 2 dirs * RT * 4 gates
  const int tbf = cg * TC, tbb = 512 - (cg + 1) * TC;
  const int wmm = w / 6, wn = w % 6;  // 2x6 waves: 32 rows x 32 cols each
  constexpr int NKc = KD / 64;

  for (int tt = gid; tt < ntiles; tt += pool) {
    const int g = tt & 3;
    const int r = (tt >> 2) % RT;
    const int dir = (tt >> 2) / RT;
    const size_t ar0 = (size_t)(dir ? tbb : tbf) * 256 + r * 64;  // A row base
    const int btr0 = dir * 768 + g * 192;                         // Bt row base

    float bj[2];
#pragma unroll
    for (int j = 0; j < 2; ++j) bj[j] = bias[btr0 + wn * 32 + j * 16 + lo16];

    f32x4 acc[2][2] = {};
    uint4 a0v, b0v, b1v;

#define LDG(ko_)                                                                   \
  do {                                                                             \
    if (tid < 512) {                                                               \
      int row = tid >> 3, sl = tid & 7, ch = sl ^ (row & 7);                       \
      a0v = *(const uint4*)(in + (ar0 + row) * KD + (ko_)*64 + ch * 8);            \
    }                                                                              \
    { int row = tid >> 3, sl = tid & 7, ch = sl ^ (row & 7);                       \
      b0v = *(const uint4*)(Bt + (size_t)(btr0 + row) * KD + (ko_)*64 + ch * 8); } \
    { int idx = tid + 768; int row = idx >> 3, sl = idx & 7, ch = sl ^ (row & 7);  \
      b1v = *(const uint4*)(Bt + (size_t)(btr0 + row) * KD + (ko_)*64 + ch * 8); } \
  } while (0)

    LDG(0);
    for (int ko = 0; ko < NKc; ++ko) {
      __syncthreads();
      if (tid < 512) sm.g.A[tid] = a0v;
      sm.g.B[tid] = b0v;
      sm.g.B[tid + 768] = b1v;
      __syncthreads();
      if (ko + 1 < NKc) LDG(ko + 1);
#pragma unroll
      for (int kk = 0; kk < 2; ++kk) {
        f16x8 af[2], bf[2];
#pragma unroll
        for (int i = 0; i < 2; ++i) {
          int rowA = wmm * 32 + i * 16 + lo16;
          int slA = (kk * 4 + lhi) ^ (rowA & 7);
          af[i] = *(const f16x8*)((const char*)sm.g.A + rowA * 128 + slA * 16);
        }
#pragma unroll
        for (int j = 0; j < 2; ++j) {
          int colB = wn * 32 + j * 16 + lo16;
          int slB = (kk * 4 + lhi) ^ (colB & 7);
          bf[j] = *(const f16x8*)((const char*)sm.g.B + colB * 128 + slB * 16);
        }
#pragma unroll
        for (int i = 0; i < 2; ++i)
#pragma unroll
          for (int j = 0; j < 2; ++j)
            acc[i][j] = __builtin_amdgcn_mfma_f32_16x16x32_f16(af[i], bf[j], acc[i][j], 0, 0, 0);
      }
    }
#undef LDG

    // epilogue -> gxW: one dwordx2 per (i,j) at seg*512 + l*8 + g*2
#pragma unroll
    for (int i = 0; i < 2; ++i) {
      int rl = r * 64 + wmm * 32 + i * 16 + lhi * 4;
      int tl = rl >> 8;
      int b16 = (rl & 255) >> 4;
#pragma unroll
      for (int j = 0; j < 2; ++j) {
        int w12 = wn * 2 + j;
        size_t seg = ((size_t)(dir * TC + tl) * 16 + b16) * 12 + w12;
        union { f16 h[2]; u32 u; } q0, q1;
        q0.h[0] = (f16)(acc[i][j][0] + bj[j]);
        q0.h[1] = (f16)(acc[i][j][1] + bj[j]);
        q1.h[0] = (f16)(acc[i][j][2] + bj[j]);
        q1.h[1] = (f16)(acc[i][j][3] + bj[j]);
        uint2 pk; pk.x = q0.u; pk.y = q1.u;
        *(uint2*)(gxW + seg * 512 + l * 8 + g * 2) = pk;
      }
    }
    __syncthreads();  // protect LDS reuse across tile loop
  }
}

__global__ void fck(const float* __restrict__ hT, const float* __restrict__ w,
                    const float* __restrict__ fb, float* __restrict__ out) {
  int b = blockIdx.x * 64 + threadIdx.x;
  float a = fb[0];
#pragma unroll 4
  for (int u = 0; u < 192; ++u)
    a += w[u] * hT[(size_t)b * 192 + u] + w[192 + u] * hT[49152 + (size_t)b * 192 + u];
  out[b] = a;
}

extern "C" void kernel_launch(void* const* d_in, const int* in_sizes, int n_in,
                              void* d_out, int out_size, void* d_ws, size_t ws_size,
                              hipStream_t stream) {
  (void)in_sizes; (void)n_in; (void)out_size;
  const int* x = (const int*)d_in[0];
  const float* emb = (const float*)d_in[1];
  const float* Wih0 = (const float*)d_in[2];
  const float* Whh0 = (const float*)d_in[3];
  const float* b0 = (const float*)d_in[4];
  const float* Wihr = (const float*)d_in[5];
  const float* Whhr = (const float*)d_in[6];
  const float* br = (const float*)d_in[7];
  const float* fcw = (const float*)d_in[8];
  const float* fcb = (const float*)d_in[9];
  float* out = (float*)d_out;

  const size_t hB = 100663296ull;  // [512][256][384] f16
  const size_t fixedB = 2 * hB + 1179648ull + 589824ull + 393216ull + 196608ull + 393216ull;

  int TC = (ws_size >= fixedB + 2ull * 16 * 786432ull) ? 16 : 8;  // TC=16 proven fit
  const int NC = 512 / TC;
  const size_t chunkB = (size_t)TC * 786432ull;

  char* ws = (char*)d_ws;
  u32* gxb[2] = {(u32*)ws, (u32*)(ws + chunkB)};
  size_t off = 2 * chunkB;
  f16* h0 = (f16*)(ws + off); off += hB;
  f16* h1 = (f16*)(ws + off); off += hB;
  f16* A0 = h1;  // alias: A0 dead before h1's first write (layer-1 lstm)
  f16* Bt = (f16*)(ws + off); off += 1179648ull;     // [1536][KD] f16 (per-layer)
  f16* whh16 = (f16*)(ws + off); off += 589824ull;   // fragment layout (per-layer)
  float* hT = (float*)(ws + off); off += 393216ull;  // [2][256][192] f32
  f16* carh = (f16*)(ws + off); off += 196608ull;
  float* carc = (float*)(ws + off); off += 393216ull;

  embedk<<<16384, 256, 0, stream>>>(x, emb, A0);

  for (int layer = 0; layer < 3; ++layer) {
    const f16* in = (layer == 0) ? A0 : (layer == 1 ? h0 : h1);
    f16* outp = (layer == 1) ? h1 : h0;  // layer 2: unused (wOut=0)
    const int wOut = (layer < 2) ? 1 : 0;
    const int wHT = (layer == 2) ? 1 : 0;
    const float* bias = (layer == 0) ? b0 : (br + (layer - 1) * 1536);

    if (layer == 0)
      castboth<<<(196608 + 294912 + 255) / 256, 256, 0, stream>>>(Wih0, Bt, 196608, Whh0, whh16);
    else
      castboth<<<(589824 + 294912 + 255) / 256, 256, 0, stream>>>(
          Wihr + (size_t)(layer - 1) * 589824, Bt, 589824,
          Whhr + (size_t)(layer - 1) * 294912, whh16);

    // prologue: gemm chunk 0 with all 256 WGs
    if (layer == 0)
      fusedk<128><<<256, 768, 0, stream>>>(in, Bt, bias, gxb[0], gxb[0], whh16,
                                           outp, hT, carh, carc, 0, 0, NC, TC, 0, wOut, wHT);
    else
      fusedk<384><<<256, 768, 0, stream>>>(in, Bt, bias, gxb[0], gxb[0], whh16,
                                           outp, hT, carh, carc, 0, 0, NC, TC, 0, wOut, wHT);

    for (int c = 0; c < NC; ++c) {
      const u32* gR = gxb[c & 1];
      u32* gW = gxb[(c + 1) & 1];
      if (layer == 0)
        fusedk<128><<<256, 768, 0, stream>>>(in, Bt, bias, gR, gW, whh16,
                                             outp, hT, carh, carc, c, c + 1, NC, TC, 1, wOut, wHT);
      else
        fusedk<384><<<256, 768, 0, stream>>>(in, Bt, bias, gR, gW, whh16,
                                             outp, hT, carh, carc, c, c + 1, NC, TC, 1, wOut, wHT);
    }
  }

  fck<<<4, 64, 0, stream>>>(hT, fcw, fcb, out);
}

// Round 13
// 2813.195 us; speedup vs baseline: 1.8966x; 1.0371x over previous
//
#include <hip/hip_runtime.h>
#include <hip/hip_bf16.h>

// LSTM_66443144069713: 3-layer biLSTM, B=256 T=512 H=192 E=128, V=20000.
// Round-13: r10 structure verbatim (proven fastest: 2779us). Only changes:
// (1) all 3 layers' weight prep in ONE upfront launch (6 launches -> 1),
// (2) compile-time peel of the chunk's last step (carry stores),
// (3) nothing else -- r12 proved the r10 inner loop is a local optimum
//     (gx layout change caused partial-line writes; fused trans is a wash).

typedef _Float16 f16;
typedef unsigned int u32;
typedef _Float16 f16x8 __attribute__((ext_vector_type(8)));
typedef float f32x4 __attribute__((ext_vector_type(4)));

__device__ __forceinline__ float sigm(float x) {
  float e = __builtin_amdgcn_exp2f(x * -1.44269504088896f);
  return __builtin_amdgcn_rcpf(1.0f + e);
}
__device__ __forceinline__ float tanh_(float x) {
  float e = __builtin_amdgcn_exp2f(x * -2.88539008177793f);
  return __builtin_fmaf(2.0f, __builtin_amdgcn_rcpf(1.0f + e), -1.0f);
}

// ---------- weight prep: all 3 layers in one launch ----------
// Bt slots: 3 x 589824 f16 (layer 0 uses first 196608). whh16: 3 x 294912 f16,
// fragment layout [dir][w12][g][kk][lane][8].
__global__ void prepw(const float* __restrict__ Wih0, const float* __restrict__ Whh0,
                      const float* __restrict__ Wihr, const float* __restrict__ Whhr,
                      f16* __restrict__ Bt, f16* __restrict__ whh16) {
  int i = blockIdx.x * 256 + threadIdx.x;  // < 2260992
  int layer, o, isWhh;
  const float* src;
  f16* dst;
  if (i < 491520) {
    layer = 0;
    o = i;
    if (o < 196608) { isWhh = 0; src = Wih0; dst = Bt; }
    else { o -= 196608; isWhh = 1; src = Whh0; dst = whh16; }
  } else {
    int j = i - 491520;
    layer = 1 + j / 884736;
    o = j % 884736;
    if (o < 589824) {
      isWhh = 0;
      src = Wihr + (size_t)(layer - 1) * 589824;
      dst = Bt + (size_t)layer * 589824;
    } else {
      o -= 589824;
      isWhh = 1;
      src = Whhr + (size_t)(layer - 1) * 294912;
      dst = whh16 + (size_t)layer * 294912;
    }
  }
  if (!isWhh) {
    dst[o] = (f16)src[o];
  } else {
    int e = o & 7, rest = o >> 3;
    int l = rest & 63; rest >>= 6;
    int kk = rest % 6; rest /= 6;
    int g = rest & 3; rest >>= 2;
    int w = rest % 12; int dir = rest / 12;
    int lo16 = l & 15, lhi = l >> 4;
    dst[o] = (f16)src[(size_t)(dir * 768 + g * 192 + w * 16 + lo16) * 192 + kk * 32 + lhi * 8 + e];
  }
}

// A0[t*256+b][k] = fp16(emb[x[b][t]][k])
__global__ void embedk(const int* __restrict__ x, const float* __restrict__ emb,
                       f16* __restrict__ A0) {
  int row = blockIdx.x * 8 + (threadIdx.x >> 5);
  int t = row >> 8, b = row & 255;
  int xi = x[b * 512 + t];
  int c = (threadIdx.x & 31) * 4;
  float4 v = *(const float4*)(emb + (size_t)xi * 128 + c);
  union { f16 h[4]; uint2 u; } p;
  p.h[0] = (f16)v.x; p.h[1] = (f16)v.y; p.h[2] = (f16)v.z; p.h[3] = (f16)v.w;
  *(uint2*)(A0 + (size_t)row * 128 + c) = p.u;
}

// ---------- fused kernel ----------
// gx dword index: ((((dir*TC+tl)*16 + b16)*12 + w12)*512) + (g*2+qq)*64 + lane,
//   lane = ((b&15)>>2)*16 + (u&15); dword packs batch rows 2qq (lo), 2qq+1 (hi).
template <int KD>
__global__ __launch_bounds__(768)
void fusedk(const f16* __restrict__ in, const f16* __restrict__ Bt,
            const float* __restrict__ bias,
            const u32* __restrict__ gxR, u32* __restrict__ gxW,
            const f16* __restrict__ whh16,
            f16* __restrict__ outh, float* __restrict__ hT,
            f16* __restrict__ carh, float* __restrict__ carc,
            int c, int cg, int NC, int TC, int doLstm, int wOut, int wHT) {
  union SMem {
    struct { uint4 A[512]; uint4 B[1536]; } g;   // 8KB + 24KB gemm staging
    f16 hb[2][16 * 200];                         // 12.8KB recurrence h
  };
  __shared__ __align__(16) SMem sm;
  const int wg = blockIdx.x;
  const int tid = threadIdx.x;
  const int l = tid & 63, w = tid >> 6;
  const int lo16 = l & 15, lhi = l >> 4;
  const int TCm1 = TC - 1;

  if (doLstm && wg < 32) {
    // ================= recurrence part (chunk c) =================
    const int dir = wg & 1, bblk = wg >> 1;
    const int u0 = w * 16;
    const int bb = bblk * 16 + lhi * 4;
    const int dc = dir * 192;
    const int hb0 = lhi * 800 + u0 + lo16;  // (lhi*4)*200 + ...

    f16x8 wf[4][6];
#pragma unroll
    for (int g = 0; g < 4; ++g)
#pragma unroll
      for (int kk = 0; kk < 6; ++kk)
        wf[g][kk] = *(const f16x8*)(whh16 + ((((size_t)dir * 12 + w) * 4 + g) * 6 + kk) * 512 + l * 8);

    float cq[4];
    if (c == 0) {
      f16* hz = (f16*)sm.hb;
      for (int i = tid; i < 2 * 16 * 200; i += 768) hz[i] = (f16)0.f;
#pragma unroll
      for (int q = 0; q < 4; ++q) cq[q] = 0.f;
    } else {
#pragma unroll
      for (int q = 0; q < 4; ++q) {
        size_t ci = ((size_t)dir * 256 + bb + q) * 192 + u0 + lo16;
        cq[q] = carc[ci];
        sm.hb[0][(lhi * 4 + q) * 200 + u0 + lo16] = carh[ci];
      }
    }
    __syncthreads();

    const int tb0 = dir ? (511 - c * TC) : (c * TC);
    f16* outp = outh + ((size_t)tb0 * 256 + bb) * 384 + dc + u0 + lo16;
    const ptrdiff_t ostep = dir ? -(ptrdiff_t)98304 : (ptrdiff_t)98304;

    u32 ga[8], gb[8];
    {  // prefetch step 0
      const int tl0 = dir ? TCm1 : 0;
      size_t wb = ((((size_t)dir * TC + tl0) * 16 + bblk) * 12 + w) * 512;
#pragma unroll
      for (int k2 = 0; k2 < 8; ++k2) ga[k2] = gxR[wb + k2 * 64 + l];
    }

#define RSTEP(S, CUR, NXT, LAST)                                                   \
  do {                                                                             \
    {                                                                              \
      int snx = ((S) + 1 < TC) ? (S) + 1 : (S);                                    \
      int tln = dir ? (TCm1 - snx) : snx;                                          \
      size_t wb = ((((size_t)dir * TC + tln) * 16 + bblk) * 12 + w) * 512;         \
      _Pragma("unroll") for (int k2 = 0; k2 < 8; ++k2) NXT[k2] = gxR[wb + k2 * 64 + l]; \
    }                                                                              \
    f32x4 ac[4];                                                                   \
    _Pragma("unroll") for (int g_ = 0; g_ < 4; ++g_) {                             \
      union { u32 u; f16 h[2]; } p0, p1;                                           \
      p0.u = CUR[2 * g_]; p1.u = CUR[2 * g_ + 1];                                  \
      ac[g_][0] = (float)p0.h[0]; ac[g_][1] = (float)p0.h[1];                      \
      ac[g_][2] = (float)p1.h[0]; ac[g_][3] = (float)p1.h[1];                      \
    }                                                                              \
    {                                                                              \
      const f16* hcur = sm.hb[(S) & 1];                                            \
      _Pragma("unroll") for (int kk = 0; kk < 6; ++kk) {                           \
        f16x8 av = *(const f16x8*)(hcur + lo16 * 200 + kk * 32 + lhi * 8);         \
        ac[0] = __builtin_amdgcn_mfma_f32_16x16x32_f16(av, wf[0][kk], ac[0], 0, 0, 0); \
        ac[1] = __builtin_amdgcn_mfma_f32_16x16x32_f16(av, wf[1][kk], ac[1], 0, 0, 0); \
        ac[2] = __builtin_amdgcn_mfma_f32_16x16x32_f16(av, wf[2][kk], ac[2], 0, 0, 0); \
        ac[3] = __builtin_amdgcn_mfma_f32_16x16x32_f16(av, wf[3][kk], ac[3], 0, 0, 0); \
      }                                                                            \
    }                                                                              \
    f16* hnew = sm.hb[((S) + 1) & 1];                                              \
    _Pragma("unroll") for (int q = 0; q < 4; ++q) {                                \
      float iv = sigm(ac[0][q]), fv = sigm(ac[1][q]);                              \
      float gv = tanh_(ac[2][q]), ov = sigm(ac[3][q]);                             \
      cq[q] = fv * cq[q] + iv * gv;                                                \
      float hv = ov * tanh_(cq[q]);                                                \
      f16 hh = (f16)hv;                                                            \
      hnew[hb0 + q * 200] = hh;                                                    \
      if (wOut) outp[q * 384] = hh;                                                \
      if (LAST) {                                                                  \
        size_t ci = ((size_t)dir * 256 + bb + q) * 192 + u0 + lo16;                \
        carh[ci] = hh;                                                             \
        carc[ci] = cq[q];                                                          \
        if (wHT && c == NC - 1) hT[ci] = hv;                                       \
      }                                                                            \
    }                                                                              \
    outp += ostep;                                                                 \
    asm volatile("s_waitcnt lgkmcnt(0)" ::: "memory");                             \
    __builtin_amdgcn_s_barrier();                                                  \
    asm volatile("" ::: "memory");                                                 \
  } while (0)

    for (int s = 0; s < TC - 2; s += 2) {
      RSTEP(s, ga, gb, 0);
      RSTEP(s + 1, gb, ga, 0);
    }
    RSTEP(TC - 2, ga, gb, 0);
    RSTEP(TC - 1, gb, ga, 1);
#undef RSTEP
    return;
  }

  // ================= GEMM part (chunk cg -> gxW), 64-row tiles =================
  if (cg >= NC) return;
  const int pool = doLstm ? 224 : 256;
  const int gid = doLstm ? wg - 32 : wg;
  const int RT = TC * 4;          // 64-row tiles per direction
  const int ntiles = RT * 8;      // 2 dirs * RT * 4 gates
  const int tbf = cg * TC, tbb = 512 - (cg + 1) * TC;
  const int wmm = w / 6, wn = w % 6;  // 2x6 waves: 32 rows x 32 cols each
  constexpr int NKc = KD / 64;

  for (int tt = gid; tt < ntiles; tt += pool) {
    const int g = tt & 3;
    const int r = (tt >> 2) % RT;
    const int dir = (tt >> 2) / RT;
    const size_t ar0 = (size_t)(dir ? tbb : tbf) * 256 + r * 64;  // A row base
    const int btr0 = dir * 768 + g * 192;                         // Bt row base

    float bj[2];
#pragma unroll
    for (int j = 0; j < 2; ++j) bj[j] = bias[btr0 + wn * 32 + j * 16 + lo16];

    f32x4 acc[2][2] = {};
    uint4 a0v, b0v, b1v;

#define LDG(ko_)                                                                   \
  do {                                                                             \
    if (tid < 512) {                                                               \
      int row = tid >> 3, sl = tid & 7, ch = sl ^ (row & 7);                       \
      a0v = *(const uint4*)(in + (ar0 + row) * KD + (ko_)*64 + ch * 8);            \
    }                                                                              \
    { int row = tid >> 3, sl = tid & 7, ch = sl ^ (row & 7);                       \
      b0v = *(const uint4*)(Bt + (size_t)(btr0 + row) * KD + (ko_)*64 + ch * 8); } \
    { int idx = tid + 768; int row = idx >> 3, sl = idx & 7, ch = sl ^ (row & 7);  \
      b1v = *(const uint4*)(Bt + (size_t)(btr0 + row) * KD + (ko_)*64 + ch * 8); } \
  } while (0)

    LDG(0);
    for (int ko = 0; ko < NKc; ++ko) {
      __syncthreads();
      if (tid < 512) sm.g.A[tid] = a0v;
      sm.g.B[tid] = b0v;
      sm.g.B[tid + 768] = b1v;
      __syncthreads();
      if (ko + 1 < NKc) LDG(ko + 1);
#pragma unroll
      for (int kk = 0; kk < 2; ++kk) {
        f16x8 af[2], bf[2];
#pragma unroll
        for (int i = 0; i < 2; ++i) {
          int rowA = wmm * 32 + i * 16 + lo16;
          int slA = (kk * 4 + lhi) ^ (rowA & 7);
          af[i] = *(const f16x8*)((const char*)sm.g.A + rowA * 128 + slA * 16);
        }
#pragma unroll
        for (int j = 0; j < 2; ++j) {
          int colB = wn * 32 + j * 16 + lo16;
          int slB = (kk * 4 + lhi) ^ (colB & 7);
          bf[j] = *(const f16x8*)((const char*)sm.g.B + colB * 128 + slB * 16);
        }
#pragma unroll
        for (int i = 0; i < 2; ++i)
#pragma unroll
          for (int j = 0; j < 2; ++j)
            acc[i][j] = __builtin_amdgcn_mfma_f32_16x16x32_f16(af[i], bf[j], acc[i][j], 0, 0, 0);
      }
    }
#undef LDG

    // epilogue -> gxW (coalesced u32 stores, dense 256B per wave)
#pragma unroll
    for (int i = 0; i < 2; ++i) {
      int rl = r * 64 + wmm * 32 + i * 16 + lhi * 4;
      int tl = rl >> 8;
      int b16 = (rl & 255) >> 4;
#pragma unroll
      for (int j = 0; j < 2; ++j) {
        int w12 = wn * 2 + j;
        size_t base = ((((size_t)dir * TC + tl) * 16 + b16) * 12 + w12) * 512;
#pragma unroll
        for (int qq = 0; qq < 2; ++qq) {
          union { f16 h[2]; u32 u; } p;
          p.h[0] = (f16)(acc[i][j][2 * qq] + bj[j]);
          p.h[1] = (f16)(acc[i][j][2 * qq + 1] + bj[j]);
          gxW[base + (g * 2 + qq) * 64 + l] = p.u;
        }
      }
    }
    __syncthreads();  // protect LDS reuse across tile loop
  }
}

__global__ void fck(const float* __restrict__ hT, const float* __restrict__ w,
                    const float* __restrict__ fb, float* __restrict__ out) {
  int b = blockIdx.x * 64 + threadIdx.x;
  float a = fb[0];
#pragma unroll 4
  for (int u = 0; u < 192; ++u)
    a += w[u] * hT[(size_t)b * 192 + u] + w[192 + u] * hT[49152 + (size_t)b * 192 + u];
  out[b] = a;
}

extern "C" void kernel_launch(void* const* d_in, const int* in_sizes, int n_in,
                              void* d_out, int out_size, void* d_ws, size_t ws_size,
                              hipStream_t stream) {
  (void)in_sizes; (void)n_in; (void)out_size;
  const int* x = (const int*)d_in[0];
  const float* emb = (const float*)d_in[1];
  const float* Wih0 = (const float*)d_in[2];
  const float* Whh0 = (const float*)d_in[3];
  const float* b0 = (const float*)d_in[4];
  const float* Wihr = (const float*)d_in[5];
  const float* Whhr = (const float*)d_in[6];
  const float* br = (const float*)d_in[7];
  const float* fcw = (const float*)d_in[8];
  const float* fcb = (const float*)d_in[9];
  float* out = (float*)d_out;

  const size_t hB = 100663296ull;  // [512][256][384] f16
  // fixed: 2 h buffers + Bt[3] + whh16[3] + hT + carh + carc
  const size_t fixedB = 2 * hB + 3538944ull + 1769472ull + 393216ull + 196608ull + 393216ull;

  int TC = (ws_size >= fixedB + 2ull * 16 * 786432ull) ? 16 : 8;  // TC=16 proven fit
  const int NC = 512 / TC;
  const size_t chunkB = (size_t)TC * 786432ull;

  char* ws = (char*)d_ws;
  u32* gxb[2] = {(u32*)ws, (u32*)(ws + chunkB)};
  size_t off = 2 * chunkB;
  f16* h0 = (f16*)(ws + off); off += hB;
  f16* h1 = (f16*)(ws + off); off += hB;
  f16* A0 = h1;  // alias: A0 dead before h1's first write (layer-1 lstm)
  f16* Bt3 = (f16*)(ws + off); off += 3538944ull;    // 3 x [1536][<=384] f16
  f16* whh3 = (f16*)(ws + off); off += 1769472ull;   // 3 x fragment layout
  float* hT = (float*)(ws + off); off += 393216ull;  // [2][256][192] f32
  f16* carh = (f16*)(ws + off); off += 196608ull;
  float* carc = (float*)(ws + off); off += 393216ull;

  embedk<<<16384, 256, 0, stream>>>(x, emb, A0);
  prepw<<<8832, 256, 0, stream>>>(Wih0, Whh0, Wihr, Whhr, Bt3, whh3);

  for (int layer = 0; layer < 3; ++layer) {
    const f16* in = (layer == 0) ? A0 : (layer == 1 ? h0 : h1);
    f16* outp = (layer == 1) ? h1 : h0;  // layer 2: unused (wOut=0)
    const int wOut = (layer < 2) ? 1 : 0;
    const int wHT = (layer == 2) ? 1 : 0;
    const float* bias = (layer == 0) ? b0 : (br + (layer - 1) * 1536);
    const f16* Bt = Bt3 + (size_t)layer * 589824;
    const f16* whh16 = whh3 + (size_t)layer * 294912;

    // prologue: gemm chunk 0 with all 256 WGs
    if (layer == 0)
      fusedk<128><<<256, 768, 0, stream>>>(in, Bt, bias, gxb[0], gxb[0], whh16,
                                           outp, hT, carh, carc, 0, 0, NC, TC, 0, wOut, wHT);
    else
      fusedk<384><<<256, 768, 0, stream>>>(in, Bt, bias, gxb[0], gxb[0], whh16,
                                           outp, hT, carh, carc, 0, 0, NC, TC, 0, wOut, wHT);

    for (int c = 0; c < NC; ++c) {
      const u32* gR = gxb[c & 1];
      u32* gW = gxb[(c + 1) & 1];
      if (layer == 0)
        fusedk<128><<<256, 768, 0, stream>>>(in, Bt, bias, gR, gW, whh16,
                                             outp, hT, carh, carc, c, c + 1, NC, TC, 1, wOut, wHT);
      else
        fusedk<384><<<256, 768, 0, stream>>>(in, Bt, bias, gR, gW, whh16,
                                             outp, hT, carh, carc, c, c + 1, NC, TC, 1, wOut, wHT);
    }
  }

  fck<<<4, 64, 0, stream>>>(hT, fcw, fcb, out);
}